// Round 4
// baseline (40.317 us; speedup 1.0000x reference)
//
#include <hip/hip_runtime.h>

#define F_IN    32768
#define HID     64
#define NB_OBJ  16
#define BATCH   64
#define N_AGENTS 4
#define N_ACT   13
#define NEG_SLOPE 0.01f

#define FC      64               // f-chunk width per block
#define NCHUNK  (F_IN / FC)      // 512 split-K chunks
#define BH      32               // batches per K1 block (batch-half)

typedef float f32x4 __attribute__((ext_vector_type(4)));

// static scratch: g_part[NCHUNK][BATCH][HID] = 8 MiB (L3-resident for K2)
__device__ float g_part[NCHUNK * BATCH * HID];

// ---------------------------------------------------------------------------
// K1: fused node-mean + partial GEMM. grid = 1024 (chunk x batch-half),
// block = 256 (4 waves) -> 4 blocks/CU for fine-grained phase interleave.
// ---------------------------------------------------------------------------
__global__ __launch_bounds__(256, 4)
void k_gcn_partial(const float* __restrict__ u, const float* __restrict__ w) {
    __shared__ float xbar[BH][FC + 4];      // row pitch 68 floats
    const int t     = threadIdx.x;
    const int blk   = blockIdx.x >> 1;      // f-chunk id
    const int bhalf = blockIdx.x & 1;       // batch half
    const int f0    = blk * FC;
    const int b0    = bhalf * BH;
    const int lane  = t & 63;
    const int wv    = t >> 6;               // 0..3

    // w column slice in registers: wreg[f] = w[(f0+f)*HID + lane]
    float wreg[FC];
    {
        const float* wp = w + (size_t)f0 * HID + lane;
        #pragma unroll
        for (int f = 0; f < FC; ++f) wreg[f] = wp[f * HID];
    }

    // step A: xbar[b][f] = (1/16) * sum_o u[b0+b][o][f0+f]
    // thread (b = t>>3, j = t&7): per-instruction 8 x 128 B segments.
    {
        const int b = t >> 3;               // 0..31
        const int j = t & 7;
        const float* up = u + (size_t)(b0 + b) * (NB_OBJ * F_IN) + f0 + j * 4;
        f32x4 a0 = (f32x4)(0.f);
        f32x4 a1 = (f32x4)(0.f);
        #pragma unroll
        for (int o = 0; o < NB_OBJ; ++o) {
            const float* ro = up + o * F_IN;
            f32x4 v0 = __builtin_nontemporal_load(reinterpret_cast<const f32x4*>(ro));
            f32x4 v1 = __builtin_nontemporal_load(reinterpret_cast<const f32x4*>(ro + 32));
            a0 += v0;
            a1 += v1;
        }
        const float inv = 1.0f / (float)NB_OBJ;
        a0 *= inv;
        a1 *= inv;
        *reinterpret_cast<f32x4*>(&xbar[b][j * 4])      = a0;
        *reinterpret_cast<f32x4*>(&xbar[b][32 + j * 4]) = a1;
    }
    __syncthreads();

    // step B: each wave -> 8 batches; lane = output h. xbar reads broadcast.
    {
        float* pout = g_part + (size_t)blk * (BATCH * HID) + (size_t)b0 * HID + lane;
        #pragma unroll
        for (int bb = 0; bb < 8; ++bb) {
            const int b = wv * 8 + bb;
            float acc = 0.f;
            #pragma unroll
            for (int fq = 0; fq < FC / 4; ++fq) {
                f32x4 xb = *reinterpret_cast<const f32x4*>(&xbar[b][fq * 4]);
                acc += xb.x * wreg[fq * 4 + 0];
                acc += xb.y * wreg[fq * 4 + 1];
                acc += xb.z * wreg[fq * 4 + 2];
                acc += xb.w * wreg[fq * 4 + 3];
            }
            pout[b * HID] = acc;
        }
    }
}

// ---------------------------------------------------------------------------
// K2: per-batch full split-K reduction (L3-resident partials) + heads +
// argmax gather. grid = BATCH (64), block = 512 (8 waves).
// ---------------------------------------------------------------------------
__global__ __launch_bounds__(512)
void k_tail(const float* __restrict__ gcn_b,
            const float* __restrict__ w1, const float* __restrict__ b1,
            const float* __restrict__ w2, const float* __restrict__ b2,
            const float* __restrict__ actions, float* __restrict__ out) {
    const int b = blockIdx.x;
    const int t = threadIdx.x;
    __shared__ float red[8][HID];
    __shared__ float pooled[HID];
    __shared__ float zbuf[N_AGENTS][HID];
    __shared__ float qbuf[N_AGENTS][N_ACT];

    // phase 1: pooled[h] = sum_k part[k][b][h] + gcn_b[h]
    // (kg,h): kg = t>>6 sums 64 chunks; per-instruction 256 B coalesced.
    {
        const int h  = t & 63;
        const int kg = t >> 6;   // 0..7
        const float* p = g_part + (size_t)(kg * 64) * (BATCH * HID)
                       + (size_t)b * HID + h;
        float acc = 0.f;
        #pragma unroll 16
        for (int i = 0; i < 64; ++i)
            acc += p[(size_t)i * (BATCH * HID)];
        red[kg][h] = acc;
    }
    __syncthreads();
    if (t < HID) {
        float acc = gcn_b[t];
        #pragma unroll
        for (int kg = 0; kg < 8; ++kg) acc += red[kg][t];
        pooled[t] = acc;
    }
    __syncthreads();

    // phase 2: z[a][k] = leaky(b1 + sum_h pooled[h] * w1[a][h][k])
    if (t < N_AGENTS * HID) {
        const int a = t >> 6, k = t & 63;
        const float* w1p = w1 + a * (HID * HID) + k;
        float acc = b1[a * HID + k];
        #pragma unroll
        for (int hh = 0; hh < HID; ++hh) acc += pooled[hh] * w1p[hh * HID];
        zbuf[a][k] = (acc >= 0.f) ? acc : NEG_SLOPE * acc;
    }
    __syncthreads();

    // phase 3: q[a][c] = b2 + sum_h z[a][h] * w2[a][h][c]
    if (t < N_AGENTS * N_ACT) {
        const int a = t / N_ACT, c = t % N_ACT;
        const float* w2p = w2 + a * (HID * N_ACT) + c;
        float acc = b2[a * N_ACT + c];
        #pragma unroll
        for (int hh = 0; hh < HID; ++hh) acc += zbuf[a][hh] * w2p[hh * N_ACT];
        qbuf[a][c] = acc;
    }
    __syncthreads();

    // phase 4: argmax over actions (first-max, matching jnp.argmax), gather
    if (t < N_AGENTS) {
        const float* ap = actions + ((size_t)t * BATCH + b) * N_ACT;
        int best = 0; float bv = ap[0];
        for (int c = 1; c < N_ACT; ++c) {
            float v = ap[c];
            if (v > bv) { bv = v; best = c; }
        }
        out[t * BATCH + b] = qbuf[t][best];
    }
}

extern "C" void kernel_launch(void* const* d_in, const int* in_sizes, int n_in,
                              void* d_out, int out_size, void* d_ws, size_t ws_size,
                              hipStream_t stream) {
    const float* u   = (const float*)d_in[0];
    // d_in[1] = binary_tensor: dead in the reference computation
    const float* act = (const float*)d_in[2];
    const float* gw  = (const float*)d_in[3];
    const float* gb  = (const float*)d_in[4];
    const float* w1  = (const float*)d_in[5];
    const float* b1  = (const float*)d_in[6];
    const float* w2  = (const float*)d_in[7];
    const float* b2  = (const float*)d_in[8];
    float* out = (float*)d_out;

    hipLaunchKernelGGL(k_gcn_partial, dim3(NCHUNK * 2), dim3(256), 0, stream, u, gw);
    hipLaunchKernelGGL(k_tail,        dim3(BATCH),      dim3(512), 0, stream,
                       gb, w1, b1, w2, b2, act, out);
}